// Round 1
// baseline (450.399 us; speedup 1.0000x reference)
//
#include <hip/hip_runtime.h>

#define TPB 256

// K1 LDS: x plane with (2,4) halo offsets. stride 76 (76%32=12 -> bank spread).
#define XS_STRIDE 76
#define XS_SIZE   (68 * 76)     // 5168 floats = 20.7 KB

// K2 LDS: t buffer, NO row halo (v-pass zero-pads rows in-register).
// stride 68 (68%32=4 -> bank spread).
#define TS_STRIDE 68
#define TS_SIZE   (64 * 68)     // 4352 floats = 17.4 KB

// ---------------- kernel 1: concat copy + 5x5 depthwise conv ----------------
__global__ __launch_bounds__(TPB, 4)
void lka_conv5_kernel(const float* __restrict__ x,
                      const float* __restrict__ w0, const float* __restrict__ b0,
                      float* __restrict__ out) {
    __shared__ __align__(16) float xs[XS_SIZE];
    const int tid = threadIdx.x;
    const int plane = blockIdx.x;       // b*128 + c
    const int b = plane >> 7;
    const int c = plane & 127;
    const float* xp = x + (size_t)plane * 4096;
    float* outb = out + ((size_t)b * 640 + (size_t)c) * 4096;

    {   // zero LDS (covers halo), then stage
        const float4 z4 = make_float4(0.f, 0.f, 0.f, 0.f);
        float4* u4 = (float4*)xs;
#pragma unroll
        for (int k = tid; k < XS_SIZE / 4; k += TPB) u4[k] = z4;
    }
    __syncthreads();
    {   // x plane -> LDS (b128) + free concat-copy to out block 0
        const float4* x4 = (const float4*)xp;
        float4* o4 = (float4*)outb;
#pragma unroll
        for (int s = 0; s < 4; ++s) {
            const int idx = tid + s * TPB;        // 0..1023 float4s
            const float4 v = x4[idx];
            o4[idx] = v;
            const int r = idx >> 4;               // row 0..63
            const int c0 = (idx & 15) << 2;       // col 0,4,..,60
            *(float4*)&xs[(r + 2) * XS_STRIDE + c0 + 4] = v;
        }
    }
    __syncthreads();
    {   // 5x5 conv + b0 -> out block 1 (this IS the att tensor k2 reads)
        const int i = tid >> 2;
        const int j0 = (tid & 3) << 4;
        const float* wp = w0 + c * 25;            // block-uniform -> s_loads
        const float bias = b0[c];
        float acc[16];
#pragma unroll
        for (int jj = 0; jj < 16; ++jj) acc[jj] = bias;
#pragma unroll
        for (int a = 0; a < 5; ++a) {
            float raw[24];
#pragma unroll
            for (int k = 0; k < 6; ++k)
                *(float4*)&raw[4 * k] = *(const float4*)&xs[(i + a) * XS_STRIDE + j0 + 4 * k];
#pragma unroll
            for (int bb = 0; bb < 5; ++bb) {
                const float w = wp[a * 5 + bb];
#pragma unroll
                for (int jj = 0; jj < 16; ++jj) acc[jj] += raw[jj + bb + 2] * w;
            }
        }
        float* op = outb + (size_t)128 * 4096 + i * 64 + j0;
#pragma unroll
        for (int q = 0; q < 4; ++q)
            ((float4*)op)[q] = make_float4(acc[4 * q], acc[4 * q + 1],
                                           acc[4 * q + 2], acc[4 * q + 3]);
    }
}

// ---------------- kernel 2: one block per (plane, branch) ----------------
// H pass reads att from GLOBAL (L2/L3-resident 16KB plane), writes t to LDS.
// Column zero-pad: aligned float4 loads; a float4 at col0 (col0 % 4 == 0) is
// either fully inside [0,64) or fully outside -> whole-f4 clamp+mask is exact.
// V pass zero-pads rows in-register (clamped LDS address + select).
template <int K>
__device__ __forceinline__ void branch_pass(
    const int tid, const int c,
    const float* __restrict__ att,                // global att plane (64x64)
    const float* __restrict__ wh, const float* __restrict__ bh,
    const float* __restrict__ wv, const float* __restrict__ bv,
    float* __restrict__ op0, float* __restrict__ t) {
    constexpr int T = 2 * K + 1;
    constexpr int KA = K + 1;                     // K ≡ 3 (mod 4) -> KA % 4 == 0
    constexpr int NW4 = (KA + 16 + K + 3) / 4;    // ceil(span/4) float4 loads
    constexpr int W = 16 + 2 * K;

    // ---- H pass ----
    {
        const int i = tid >> 2;
        const int j0 = (tid & 3) << 4;
        const float* arow = att + i * 64;
        float raw[4 * NW4];
#pragma unroll
        for (int q = 0; q < NW4; ++q) {
            const int col0 = j0 - KA + 4 * q;
            const bool ok = (unsigned)col0 < 61u;           // col0 in [0,60]
            const float4 v = *(const float4*)&arow[ok ? col0 : 0];
            raw[4 * q + 0] = ok ? v.x : 0.f;
            raw[4 * q + 1] = ok ? v.y : 0.f;
            raw[4 * q + 2] = ok ? v.z : 0.f;
            raw[4 * q + 3] = ok ? v.w : 0.f;
        }
        const float* whp = wh + c * T;            // block-uniform -> s_loads
        const float bias = bh[c];
        float acc[16];
#pragma unroll
        for (int jj = 0; jj < 16; ++jj) acc[jj] = bias;
#pragma unroll
        for (int d = 0; d < T; ++d) {
            const float w = whp[d];
#pragma unroll
            for (int jj = 0; jj < 16; ++jj) acc[jj] += raw[jj + d + 1] * w;
        }
#pragma unroll
        for (int q = 0; q < 4; ++q)
            *(float4*)&t[i * TS_STRIDE + j0 + 4 * q] =
                make_float4(acc[4 * q], acc[4 * q + 1], acc[4 * q + 2], acc[4 * q + 3]);
    }
    __syncthreads();

    // ---- V pass ----
    {
        const int j = tid & 63;
        const int i0 = (tid >> 6) << 4;           // wave-uniform 0,16,32,48
        float win[W];
#pragma unroll
        for (int dd = 0; dd < W; ++dd) {
            const int r = i0 - K + dd;
            const int rc = min(max(r, 0), 63);
            const float v = t[rc * TS_STRIDE + j]; // always-valid address
            win[dd] = (r == rc) ? v : 0.f;         // zero row-pad
        }
        const float* wvp = wv + c * T;
        const float bias = bv[c];
        float acc[16];
#pragma unroll
        for (int ii = 0; ii < 16; ++ii) acc[ii] = bias;
#pragma unroll
        for (int d = 0; d < T; ++d) {
            const float w = wvp[d];
#pragma unroll
            for (int ii = 0; ii < 16; ++ii) acc[ii] += win[ii + d] * w;
        }
        float* op = op0 + i0 * 64 + j;
#pragma unroll
        for (int ii = 0; ii < 16; ++ii) op[ii * 64] = acc[ii];
    }
}

__global__ __launch_bounds__(TPB, 4)
void lka_branch_kernel(float* out,                 // no __restrict__: reads+writes out
                       const float* __restrict__ w01, const float* __restrict__ b01,
                       const float* __restrict__ w02, const float* __restrict__ b02,
                       const float* __restrict__ w11, const float* __restrict__ b11,
                       const float* __restrict__ w12, const float* __restrict__ b12,
                       const float* __restrict__ w21, const float* __restrict__ b21,
                       const float* __restrict__ w22, const float* __restrict__ b22) {
    __shared__ __align__(16) float t[TS_SIZE];
    const int tid = threadIdx.x;
    const int plane = blockIdx.x;                  // b*128 + c
    const int b = plane >> 7;
    const int c = plane & 127;
    const float* att = out + ((size_t)b * 640 + 128 + (size_t)c) * 4096;
    float* op = out + ((size_t)b * 640 + (size_t)(2 + blockIdx.y) * 128 + (size_t)c) * 4096;

    if (blockIdx.y == 0)
        branch_pass<3>(tid, c, att, w01, b01, w02, b02, op, t);
    else if (blockIdx.y == 1)
        branch_pass<7>(tid, c, att, w11, b11, w12, b12, op, t);
    else
        branch_pass<15>(tid, c, att, w21, b21, w22, b22, op, t);
}

extern "C" void kernel_launch(void* const* d_in, const int* in_sizes, int n_in,
                              void* d_out, int out_size, void* d_ws, size_t ws_size,
                              hipStream_t stream) {
    const float* x   = (const float*)d_in[0];
    const float* w0  = (const float*)d_in[1];
    const float* b0  = (const float*)d_in[2];
    const float* w01 = (const float*)d_in[3];
    const float* b01 = (const float*)d_in[4];
    const float* w02 = (const float*)d_in[5];
    const float* b02 = (const float*)d_in[6];
    const float* w11 = (const float*)d_in[7];
    const float* b11 = (const float*)d_in[8];
    const float* w12 = (const float*)d_in[9];
    const float* b12 = (const float*)d_in[10];
    const float* w21 = (const float*)d_in[11];
    const float* b21 = (const float*)d_in[12];
    const float* w22 = (const float*)d_in[13];
    const float* b22 = (const float*)d_in[14];
    float* out = (float*)d_out;

    lka_conv5_kernel<<<dim3(4096), dim3(TPB), 0, stream>>>(x, w0, b0, out);
    lka_branch_kernel<<<dim3(4096, 3), dim3(TPB), 0, stream>>>(
        out, w01, b01, w02, b02, w11, b11, w12, b12, w21, b21, w22, b22);
}

// Round 2
// 417.312 us; speedup vs baseline: 1.0793x; 1.0793x over previous
//
#include <hip/hip_runtime.h>

#define TPB 256

// Two plain 64x64 LDS planes, stride 68 floats (68%32=4 -> bank spread, 16B aligned).
// Buffer A holds x during conv5, then is reused as the h-pass output t.
// Buffer B holds att (conv5 output) for all three branches.
// No halos anywhere: column zero-pad via whole-float4 clamp+mask (pad regions are
// 4-float aligned), row zero-pad via clamped address + select.
#define TS_STRIDE 68
#define TS_SIZE   (64 * 68)     // 4352 floats = 17 KB; two buffers = 34 KB

// lgkm-only barrier: do NOT drain vmcnt. Global stores from the previous phase
// are never read inside the kernel, so they may stay in flight across barriers
// (their ~900cy HBM latency overlaps the next compute phase).
__device__ __forceinline__ void sync_lds() {
    asm volatile("s_waitcnt lgkmcnt(0)" ::: "memory");
    __builtin_amdgcn_s_barrier();
}

// Horizontal 1x(2K+1) pass: reads att (LDS B), writes t (LDS A).
template <int K>
__device__ __forceinline__ void h_pass(const int tid, const int c,
                                       const float* __restrict__ att,
                                       const float* __restrict__ wh,
                                       const float* __restrict__ bh,
                                       float* __restrict__ t) {
    constexpr int T = 2 * K + 1;
    constexpr int KA = K + 1;                    // K ≡ 3 (mod 4) -> KA % 4 == 0
    constexpr int NW4 = (KA + 16 + K + 3) / 4;   // 6 / 8 / 12 for K=3/7/15
    const int i = tid >> 2;
    const int j0 = (tid & 3) << 4;
    const float* wp = wh + c * T;                // block-uniform -> s_load
    const float bias = bh[c];
    const float* arow = att + i * TS_STRIDE;
    float raw[4 * NW4];
#pragma unroll
    for (int q = 0; q < NW4; ++q) {
        const int col0 = j0 - KA + 4 * q;
        const bool ok = (unsigned)col0 < 61u;    // col0 in [0,60]
        const float4 v = *(const float4*)&arow[ok ? col0 : 0];
        raw[4 * q + 0] = ok ? v.x : 0.f;
        raw[4 * q + 1] = ok ? v.y : 0.f;
        raw[4 * q + 2] = ok ? v.z : 0.f;
        raw[4 * q + 3] = ok ? v.w : 0.f;
    }
    float acc[16];
#pragma unroll
    for (int jj = 0; jj < 16; ++jj) acc[jj] = bias;
#pragma unroll
    for (int d = 0; d < T; ++d) {
        const float w = wp[d];
#pragma unroll
        for (int jj = 0; jj < 16; ++jj) acc[jj] += raw[jj + d + 1] * w;  // KA-K = 1
    }
#pragma unroll
    for (int q = 0; q < 4; ++q)
        *(float4*)&t[i * TS_STRIDE + j0 + 4 * q] =
            make_float4(acc[4 * q], acc[4 * q + 1], acc[4 * q + 2], acc[4 * q + 3]);
}

// Vertical (2K+1)x1 pass: reads t (LDS A), writes one concat block of out.
template <int K>
__device__ __forceinline__ void v_pass(const int tid, const int c,
                                       const float* __restrict__ t,
                                       const float* __restrict__ wv,
                                       const float* __restrict__ bv,
                                       float* __restrict__ op0) {
    constexpr int T = 2 * K + 1;
    constexpr int W = 16 + 2 * K;
    const int j = tid & 63;
    const int i0 = (tid >> 6) << 4;              // wave-uniform 0,16,32,48
    const float* wp = wv + c * T;
    const float bias = bv[c];
    float win[W];
#pragma unroll
    for (int dd = 0; dd < W; ++dd) {
        const int r = i0 - K + dd;
        const int rc = min(max(r, 0), 63);
        const float v = t[rc * TS_STRIDE + j];   // always-valid address
        win[dd] = (r == rc) ? v : 0.f;           // zero row-pad
    }
    float acc[16];
#pragma unroll
    for (int ii = 0; ii < 16; ++ii) acc[ii] = bias;
#pragma unroll
    for (int d = 0; d < T; ++d) {
        const float w = wp[d];
#pragma unroll
        for (int ii = 0; ii < 16; ++ii) acc[ii] += win[ii + d] * w;
    }
    float* op = op0 + i0 * 64 + j;
#pragma unroll
    for (int ii = 0; ii < 16; ++ii) op[ii * 64] = acc[ii];
}

__global__ __launch_bounds__(TPB, 4)
void lka_fused_kernel(const float* __restrict__ x,
                      const float* __restrict__ w0,  const float* __restrict__ b0,
                      const float* __restrict__ w01, const float* __restrict__ b01,
                      const float* __restrict__ w02, const float* __restrict__ b02,
                      const float* __restrict__ w11, const float* __restrict__ b11,
                      const float* __restrict__ w12, const float* __restrict__ b12,
                      const float* __restrict__ w21, const float* __restrict__ b21,
                      const float* __restrict__ w22, const float* __restrict__ b22,
                      float* __restrict__ out) {
    __shared__ __align__(16) float bufA[TS_SIZE];   // x, then t
    __shared__ __align__(16) float bufB[TS_SIZE];   // att

    const int tid = threadIdx.x;
    const int plane = blockIdx.x;       // b*128 + c
    const int b = plane >> 7;
    const int c = plane & 127;

    const float* xp = x + (size_t)plane * 4096;
    float* outb = out + ((size_t)b * 640 + (size_t)c) * 4096;

    // ---- P0: x plane -> LDS A (b128) + free concat-copy to out block 0 ----
    {
        const float4* x4 = (const float4*)xp;
        float4* o4 = (float4*)outb;
#pragma unroll
        for (int s = 0; s < 4; ++s) {
            const int idx = tid + s * TPB;        // 0..1023 float4s
            const float4 v = x4[idx];
            o4[idx] = v;
            const int r = idx >> 4;               // row 0..63
            const int c0 = (idx & 15) << 2;       // col 0,4,..,60
            *(float4*)&bufA[r * TS_STRIDE + c0] = v;
        }
    }
    sync_lds();

    // ---- P1: 5x5 conv + b0 (clamp+mask pad) -> out block 1 + att (LDS B) ----
    {
        const int i = tid >> 2;
        const int j0 = (tid & 3) << 4;
        const float* wp = w0 + c * 25;            // block-uniform -> s_load
        const float bias = b0[c];
        float acc[16];
#pragma unroll
        for (int jj = 0; jj < 16; ++jj) acc[jj] = bias;
#pragma unroll
        for (int a = 0; a < 5; ++a) {
            const int r = i + a - 2;
            const int rc = min(max(r, 0), 63);
            const bool okr = (r == rc);
            const float* xrow = bufA + rc * TS_STRIDE;
            float raw[24];
#pragma unroll
            for (int k = 0; k < 6; ++k) {
                const int col0 = j0 - 4 + 4 * k;
                const bool okc = (unsigned)col0 < 61u;
                const bool ok = okr && okc;
                const float4 v = *(const float4*)&xrow[okc ? col0 : 0];
                raw[4 * k + 0] = ok ? v.x : 0.f;
                raw[4 * k + 1] = ok ? v.y : 0.f;
                raw[4 * k + 2] = ok ? v.z : 0.f;
                raw[4 * k + 3] = ok ? v.w : 0.f;
            }
#pragma unroll
            for (int bb = 0; bb < 5; ++bb) {
                const float w = wp[a * 5 + bb];
#pragma unroll
                for (int jj = 0; jj < 16; ++jj) acc[jj] += raw[jj + bb + 2] * w;
            }
        }
        float* op = outb + (size_t)128 * 4096 + i * 64 + j0;
#pragma unroll
        for (int q = 0; q < 4; ++q) {
            const float4 v = make_float4(acc[4 * q], acc[4 * q + 1],
                                         acc[4 * q + 2], acc[4 * q + 3]);
            ((float4*)op)[q] = v;
            *(float4*)&bufB[i * TS_STRIDE + j0 + 4 * q] = v;
        }
    }
    sync_lds();

    // ---- branch 0: 7-tap ----
    h_pass<3>(tid, c, bufB, w01, b01, bufA);
    sync_lds();
    v_pass<3>(tid, c, bufA, w02, b02, outb + (size_t)2 * 128 * 4096);
    sync_lds();                                   // A reads done before h7 writes A

    // ---- branch 1: 15-tap ----
    h_pass<7>(tid, c, bufB, w11, b11, bufA);
    sync_lds();
    v_pass<7>(tid, c, bufA, w12, b12, outb + (size_t)3 * 128 * 4096);
    sync_lds();

    // ---- branch 2: 31-tap ----
    h_pass<15>(tid, c, bufB, w21, b21, bufA);
    sync_lds();
    v_pass<15>(tid, c, bufA, w22, b22, outb + (size_t)4 * 128 * 4096);
}

extern "C" void kernel_launch(void* const* d_in, const int* in_sizes, int n_in,
                              void* d_out, int out_size, void* d_ws, size_t ws_size,
                              hipStream_t stream) {
    const float* x   = (const float*)d_in[0];
    const float* w0  = (const float*)d_in[1];
    const float* b0  = (const float*)d_in[2];
    const float* w01 = (const float*)d_in[3];
    const float* b01 = (const float*)d_in[4];
    const float* w02 = (const float*)d_in[5];
    const float* b02 = (const float*)d_in[6];
    const float* w11 = (const float*)d_in[7];
    const float* b11 = (const float*)d_in[8];
    const float* w12 = (const float*)d_in[9];
    const float* b12 = (const float*)d_in[10];
    const float* w21 = (const float*)d_in[11];
    const float* b21 = (const float*)d_in[12];
    const float* w22 = (const float*)d_in[13];
    const float* b22 = (const float*)d_in[14];
    float* out = (float*)d_out;

    lka_fused_kernel<<<dim3(4096), dim3(TPB), 0, stream>>>(
        x, w0, b0, w01, b01, w02, b02, w11, b11, w12, b12, w21, b21, w22, b22, out);
}